// Round 6
// baseline (4286.238 us; speedup 1.0000x reference)
//
#include <hip/hip_runtime.h>
#include <cstdint>
#include <cstddef>

#define NODES   55
#define BGRAPH  16384
#define NTOT    (BGRAPH*NODES)    // 901120
#define INCH    13
#define HID     32
#define ETOT    (4*NTOT)          // 3604480
#define NCHUNK  (NTOT/1024)       // 880 exact
#define NPB     128               // nodes per block (layer kernels)
#define LCAP    1024              // LDS csr stage capacity (mean 512, sd 23)

typedef _Float16 f16;
typedef _Float16 f16x4 __attribute__((ext_vector_type(4))); // 8B
typedef _Float16 f16x8 __attribute__((ext_vector_type(8))); // 16B

__device__ __forceinline__ float selu_f(float v){
  const float s  = 1.0507009873554805f;
  const float sa = 1.7580993408473766f;   // scale*alpha
  return v > 0.f ? s*v : sa*(__expf(v)-1.f);
}

// ---------------- CSR build ----------------
__global__ void k_hist(const int* __restrict__ dst, int* __restrict__ deg){
  int e = blockIdx.x*256 + threadIdx.x;
  if (e < ETOT) atomicAdd(&deg[dst[e]], 1);
}

__global__ void k_scan1(const int* __restrict__ deg, int* __restrict__ part){
  __shared__ int sd[256];
  int b = blockIdx.x, t = threadIdx.x;
  const int4* p = (const int4*)(deg + b*1024);
  int4 v = p[t];
  sd[t] = v.x+v.y+v.z+v.w;
  __syncthreads();
  for (int o=128;o>0;o>>=1){ if (t<o) sd[t]+=sd[t+o]; __syncthreads(); }
  if (t==0) part[b] = sd[0];
}

__global__ void k_scan2(int* __restrict__ part, int nc){
  __shared__ int sd[1024];
  int t = threadIdx.x;
  int orig = (t<nc) ? part[t] : 0;
  sd[t] = orig;
  __syncthreads();
  for (int o=1;o<1024;o<<=1){
    int v = (t>=o) ? sd[t-o] : 0;
    __syncthreads();
    sd[t] += v;
    __syncthreads();
  }
  if (t<nc) part[t] = sd[t] - orig;   // exclusive
}

__global__ void k_scan3(const int* __restrict__ deg, const int* __restrict__ part,
                        int* __restrict__ off){
  __shared__ int sd[256];
  int b = blockIdx.x, t = threadIdx.x;
  const int4* p = (const int4*)(deg + b*1024);
  int4 v = p[t];
  int s = v.x+v.y+v.z+v.w;
  sd[t] = s;
  __syncthreads();
  for (int o=1;o<256;o<<=1){
    int val = (t>=o) ? sd[t-o] : 0;
    __syncthreads();
    sd[t] += val;
    __syncthreads();
  }
  int base = part[b] + sd[t] - s;     // exclusive prefix for this thread
  int i = b*1024 + t*4;
  off[i]   = base;
  off[i+1] = base + v.x;
  off[i+2] = base + v.x + v.y;
  off[i+3] = base + v.x + v.y + v.z;
  if (b==0 && t==0) off[NTOT] = ETOT;
}

// packed entry: src (20 bits) | dst_local-within-128 (7 bits) << 20
__global__ void k_fill(const int* __restrict__ src, const int* __restrict__ dst,
                       int* __restrict__ cur, uint32_t* __restrict__ csrp){
  int e = blockIdx.x*256 + threadIdx.x;
  if (e >= ETOT) return;
  int d = dst[e];
  int pos = atomicAdd(&cur[d], 1);
  csrp[pos] = (uint32_t)src[e] | (((uint32_t)d & 127u) << 20);
}

// ---------------- fused SAGE layer 0 ----------------
// edge-parallel gather with LDS-staged csr + 8-deep independent loads
__global__ __launch_bounds__(256,8) void k_layer0(
    const float* __restrict__ x,
    const int* __restrict__ off, const uint32_t* __restrict__ csrp,
    const float* __restrict__ wl0, const float* __restrict__ bl0,
    const float* __restrict__ wr0,
    f16* __restrict__ hout, f16* __restrict__ jkout)
{
  __shared__ float AG0[NPB*INCH];    // 6.7 KB fp32 accumulators
  __shared__ f16   ST0[NPB*34];      // 8.7 KB output staging
  __shared__ uint32_t CSRL[LCAP];    // 4 KB
  int t = threadIdx.x;
  int base = blockIdx.x*NPB;
  for (int i=t; i<NPB*INCH; i+=256) AG0[i] = 0.f;
  int e0 = off[base], e1 = off[base+NPB];
  int ecnt = e1 - e0;
  for (int i=t; i<ecnt; i+=256) if (i < LCAP) CSRL[i] = csrp[e0+i];
  __syncthreads();

  int slot = t >> 4, c = t & 15;      // 16 slot-groups, lane = channel
  int nIter = (ecnt + 127) >> 7;      // 128 edges per iteration
  for (int it=0; it<nIter; it++){
    int eb = it*128 + slot*8;
    uint32_t kk[8]; bool vm[8];
    #pragma unroll
    for (int i=0;i<8;i++){
      int idx = eb + i;
      vm[i] = idx < ecnt;
      int m = vm[i] ? idx : (ecnt-1);
      kk[i] = (m < LCAP) ? CSRL[m] : csrp[e0+m];
    }
    float g[8];
    #pragma unroll
    for (int i=0;i<8;i++)
      g[i] = (c < INCH) ? x[(size_t)((kk[i]&0xFFFFFu)*INCH + c)] : 0.f;
    if (c < INCH){
      #pragma unroll
      for (int i=0;i<8;i++)
        atomicAdd(AG0 + ((kk[i]>>20)&127u)*INCH + c, vm[i]?g[i]:0.f);
    }
  }
  __syncthreads();

  // phase 2: node = base+(t&127), oc half = t>>7 (wave-uniform)
  int nl = t & 127;
  int node = base + nl;
  int oc0 = __builtin_amdgcn_readfirstlane((t>>7)*16);
  int cnt = ecnt>0 ? (off[node+1]-off[node]) : 1; if (cnt < 1) cnt = 1;
  float inv = 1.f/(float)cnt;
  const float* xr = x + (size_t)node*INCH;
  float acc[16];
  #pragma unroll
  for (int j=0;j<16;j++) acc[j] = bl0[oc0+j];
  #pragma unroll
  for (int cc=0;cc<INCH;cc++){
    float xc = xr[cc];
    float mc = AG0[nl*INCH+cc]*inv;
    #pragma unroll
    for (int j=0;j<16;j++)
      acc[j] = fmaf(xc, wr0[cc*HID+oc0+j], fmaf(mc, wl0[cc*HID+oc0+j], acc[j]));
  }
  #pragma unroll
  for (int j=0;j<16;j++) ST0[nl*34 + oc0 + j] = (f16)selu_f(acc[j]);
  __syncthreads();

  const uint32_t* STd = (const uint32_t*)ST0;
  uint4* ho4 = (uint4*)hout;
  uint4* jo4 = (uint4*)jkout;
  int gbase = blockIdx.x*(NPB*HID/8);   // 512 16B-chunks per block
  #pragma unroll
  for (int k=0;k<2;k++){
    int cch = t + 256*k;
    int n = cch>>2, m = cch&3;
    int d = n*17 + m*4;
    uint4 u;
    u.x=STd[d]; u.y=STd[d+1]; u.z=STd[d+2]; u.w=STd[d+3];
    ho4[gbase+cch] = u;
    jo4[gbase+cch] = u;
  }
}

// ---------------- fused SAGE layers 1..4 ----------------
// LDS-staged csr + 8 independent 64B row-gathers in flight per wave
__global__ __launch_bounds__(256,8) void k_layer(
    const f16* __restrict__ hin,
    const int* __restrict__ off, const uint32_t* __restrict__ csrp,
    const float* __restrict__ wl, const float* __restrict__ bl,
    const float* __restrict__ wr,
    f16* __restrict__ hout, f16* __restrict__ jkio)
{
  __shared__ float AGf[NPB*33];      // 16.9 KB (accumulators, reused as staging)
  __shared__ uint32_t CSRL[LCAP];    // 4 KB
  int t = threadIdx.x;
  int base = blockIdx.x*NPB;
  for (int i=t; i<NPB*33; i+=256) AGf[i] = 0.f;
  int e0 = off[base], e1 = off[base+NPB];
  int ecnt = e1 - e0;
  for (int i=t; i<ecnt; i+=256) if (i < LCAP) CSRL[i] = csrp[e0+i];
  __syncthreads();

  int slot = t >> 3, l = t & 7;       // 32 slot-groups, 8 lanes (4 ch) per edge
  int nIter = (ecnt + 255) >> 8;      // 256 edges per iteration
  for (int it=0; it<nIter; it++){
    int eb = it*256 + slot*8;
    uint32_t kk[8]; bool vm[8];
    #pragma unroll
    for (int i=0;i<8;i++){
      int idx = eb + i;
      vm[i] = idx < ecnt;
      int m = vm[i] ? idx : (ecnt-1);
      kk[i] = (m < LCAP) ? CSRL[m] : csrp[e0+m];
    }
    f16x4 g[8];
    #pragma unroll
    for (int i=0;i<8;i++)
      g[i] = *(const f16x4*)(hin + (size_t)((kk[i]&0xFFFFFu)*32u + 4u*l));
    #pragma unroll
    for (int i=0;i<8;i++){
      float* d = AGf + ((kk[i]>>20)&127u)*33 + 4*l;
      #pragma unroll
      for (int j=0;j<4;j++) atomicAdd(d+j, vm[i]?(float)g[i][j]:0.f);
    }
  }
  __syncthreads();

  // phase 2: node = base+(t&127), oc half = t>>7 (wave-uniform -> scalar weights)
  int nl = t & 127;
  int node = base + nl;
  int oc0 = __builtin_amdgcn_readfirstlane((t>>7)*16);
  int cnt = off[node+1]-off[node]; if (cnt < 1) cnt = 1;
  float inv = 1.f/(float)cnt;
  const f16x8* h8 = (const f16x8*)(hin + (size_t)node*HID);
  float acc[16];
  #pragma unroll
  for (int j=0;j<16;j++) acc[j] = bl[oc0+j];
  #pragma unroll
  for (int jj=0;jj<4;jj++){
    f16x8 vh = h8[jj];
    #pragma unroll
    for (int r=0;r<8;r++){
      int cc = 8*jj+r;
      float hc = (float)vh[r];
      float mc = AGf[nl*33+cc]*inv;
      #pragma unroll
      for (int j=0;j<16;j++)
        acc[j] = fmaf(hc, wr[cc*HID+oc0+j], fmaf(mc, wl[cc*HID+oc0+j], acc[j]));
    }
  }
  __syncthreads();   // all AGf reads done -> safe to alias as staging
  f16* ST = (f16*)AGf;
  #pragma unroll
  for (int j=0;j<16;j++) ST[nl*34 + oc0 + j] = (f16)selu_f(acc[j]);
  __syncthreads();

  const uint32_t* STd = (const uint32_t*)AGf;
  uint4* ho4 = (uint4*)hout;
  uint4* jo4 = (uint4*)jkio;
  int gbase = blockIdx.x*(NPB*HID/8);
  #pragma unroll
  for (int k=0;k<2;k++){
    int cch = t + 256*k;
    int n = cch>>2, m = cch&3;
    int d = n*17 + m*4;
    union { uint4 u; f16 hh[8]; } hv, jv;
    hv.u.x=STd[d]; hv.u.y=STd[d+1]; hv.u.z=STd[d+2]; hv.u.w=STd[d+3];
    jv.u = jo4[gbase+cch];
    #pragma unroll
    for (int r=0;r<8;r++){
      float a = (float)jv.hh[r], b = (float)hv.hh[r];
      jv.hh[r] = (f16)fmaxf(a, b);
    }
    ho4[gbase+cch] = hv.u;
    jo4[gbase+cch] = jv.u;
  }
}

// ---------------- attention + head, one block per graph ----------------
__global__ __launch_bounds__(256) void k_attn(
    const f16* __restrict__ jk, const float* __restrict__ x,
    const int* __restrict__ shuf,
    const float* __restrict__ wq, const float* __restrict__ bq,
    const float* __restrict__ wk, const float* __restrict__ bk,
    const float* __restrict__ wv, const float* __restrict__ bv,
    const float* __restrict__ wo, const float* __restrict__ bo,
    const float* __restrict__ wfc, const float* __restrict__ bfc,
    float* __restrict__ out)
{
  __shared__ float H[NODES*33];
  __shared__ float K[NODES*33];
  __shared__ float V[NODES*33];
  __shared__ float Wq[HID*HID];
  __shared__ float Wo[HID*HID];
  __shared__ float Wfc[192*6];
  __shared__ float Qs[6*33];
  __shared__ float S[6*56];
  __shared__ float O[6*33];
  __shared__ float SO[192];
  __shared__ float part[96];
  __shared__ float M[NODES];
  __shared__ int order[8];
  __shared__ int sel[6];

  int g = blockIdx.x, t = threadIdx.x;
  for (int i=t; i<HID*HID; i+=256){ Wq[i]=wq[i]; Wo[i]=wo[i]; }
  for (int i=t; i<192*6;   i+=256){ Wfc[i]=wfc[i]; }
  {
    const f16x8* j8 = (const f16x8*)(jk + (size_t)g*NODES*HID);
    for (int i=t; i<NODES*HID/8; i+=256){     // 220 vectors of 8
      f16x8 v = j8[i];
      int node = i >> 2, c0 = (i & 3)*8;
      #pragma unroll
      for (int r=0;r<8;r++) H[node*33 + c0 + r] = selu_f((float)v[r]);
    }
  }
  if (t < NODES) M[t] = x[(size_t)(g*NODES+t)*INCH + (INCH-3)];
  __syncthreads();
  if (t == 0){
    int c = 0;
    for (int n=0;n<NODES;n++) if (M[n] > 0.5f && c < 6) order[c++] = n;
  }
  __syncthreads();
  if (t < 6) sel[t] = order[shuf[g*6 + t]];
  __syncthreads();

  // K and V: lane = node, wave-uniform output-channel group -> scalar weights
  {
    int k = t & 63;
    int ocg = __builtin_amdgcn_readfirstlane(t >> 6);   // 0..3, wave-uniform
    const float* wkp = wk + ocg*8;
    const float* wvp = wv + ocg*8;
    if (k < NODES){
      float ak[8], av[8];
      #pragma unroll
      for (int j=0;j<8;j++){ ak[j]=bk[ocg*8+j]; av[j]=bv[ocg*8+j]; }
      #pragma unroll
      for (int c=0;c<HID;c++){
        float hv = H[k*33+c];
        #pragma unroll
        for (int j=0;j<8;j++){
          ak[j] = fmaf(hv, wkp[c*HID+j], ak[j]);
          av[j] = fmaf(hv, wvp[c*HID+j], av[j]);
        }
      }
      #pragma unroll
      for (int j=0;j<8;j++){ K[k*33+ocg*8+j]=ak[j]; V[k*33+ocg*8+j]=av[j]; }
    }
  }
  // Q: 6 queries x 32 channels
  if (t < 192){
    int q = t>>5, oc = t&31;
    int node = sel[q];
    float a = bq[oc];
    #pragma unroll
    for (int c=0;c<HID;c++) a = fmaf(H[node*33+c], Wq[c*HID+oc], a);
    Qs[q*33+oc] = a;
  }
  __syncthreads();

  // scores = Q.K^T / sqrt(32)
  for (int idx=t; idx<6*NODES; idx+=256){
    int q = idx % 6, k = idx / 6;
    float a = 0.f;
    #pragma unroll
    for (int c=0;c<HID;c++) a = fmaf(Qs[q*33+c], K[k*33+c], a);
    S[q*56+k] = a * 0.17677669529663687f;
  }
  __syncthreads();

  // softmax over 55 keys: 32-lane group per query
  if (t < 192){
    int q = t>>5, l = t&31;
    float v0 = (l      < NODES) ? S[q*56+l]    : -1e30f;
    float v1 = (l+32   < NODES) ? S[q*56+l+32] : -1e30f;
    float mx = fmaxf(v0, v1);
    #pragma unroll
    for (int o=16;o>0;o>>=1) mx = fmaxf(mx, __shfl_xor(mx, o, 32));
    float p0 = (l    < NODES) ? __expf(v0-mx) : 0.f;
    float p1 = (l+32 < NODES) ? __expf(v1-mx) : 0.f;
    float sm = p0 + p1;
    #pragma unroll
    for (int o=16;o>0;o>>=1) sm += __shfl_xor(sm, o, 32);
    float inv = 1.f/sm;
    if (l    < NODES) S[q*56+l]    = p0*inv;
    if (l+32 < NODES) S[q*56+l+32] = p1*inv;
  }
  __syncthreads();

  // attn @ V
  if (t < 192){
    int q = t>>5, oc = t&31;
    float a = 0.f;
    for (int k=0;k<NODES;k++) a = fmaf(S[q*56+k], V[k*33+oc], a);
    O[q*33+oc] = a;
  }
  __syncthreads();

  // @ wo + bo, selu
  if (t < 192){
    int q = t>>5, oc = t&31;
    float a = bo[oc];
    #pragma unroll
    for (int c=0;c<HID;c++) a = fmaf(O[q*33+c], Wo[c*HID+oc], a);
    SO[t] = selu_f(a);   // t == q*32+oc == flat reshape index
  }
  __syncthreads();

  // final FC: 6 outputs = SO[192] . Wfc[:,j]
  if (t < 96){
    int j = t % 6, pp = t / 6;   // 16 partials per output
    float a = 0.f;
    #pragma unroll
    for (int r=0;r<12;r++) a = fmaf(SO[pp*12+r], Wfc[(pp*12+r)*6+j], a);
    part[pp*6+j] = a;
  }
  __syncthreads();
  if (t < 6){
    float a = bfc[t];
    #pragma unroll
    for (int pp=0;pp<16;pp++) a += part[pp*6+t];
    out[g*6+t] = a;
  }
}

extern "C" void kernel_launch(void* const* d_in, const int* in_sizes, int n_in,
                              void* d_out, int out_size, void* d_ws, size_t ws_size,
                              hipStream_t stream)
{
  const float* x   = (const float*)d_in[0];
  const int*   eix = (const int*)d_in[1];
  const int*   shf = (const int*)d_in[2];
  const float* wl0 = (const float*)d_in[3];
  const float* bl0 = (const float*)d_in[4];
  const float* wr0 = (const float*)d_in[5];
  const float* wl  = (const float*)d_in[6];
  const float* bl  = (const float*)d_in[7];
  const float* wr  = (const float*)d_in[8];
  const float* wq  = (const float*)d_in[9];
  const float* bq  = (const float*)d_in[10];
  const float* wk  = (const float*)d_in[11];
  const float* bk  = (const float*)d_in[12];
  const float* wv  = (const float*)d_in[13];
  const float* bv  = (const float*)d_in[14];
  const float* wo  = (const float*)d_in[15];
  const float* bo  = (const float*)d_in[16];
  const float* wfc = (const float*)d_in[17];
  const float* bfc = (const float*)d_in[18];
  float* out = (float*)d_out;

  const int* esrc = eix;
  const int* edst = eix + ETOT;

  // workspace carve — total ~195 MB
  char* p = (char*)d_ws;
  auto carve = [&](size_t bytes){ void* r = (void*)p; p += (bytes + 255) & ~(size_t)255; return r; };
  int*      deg  = (int*)carve(sizeof(int)*NTOT);          // reused as `cur` for k_fill
  int*      off  = (int*)carve(sizeof(int)*(NTOT+1));
  int*      part = (int*)carve(sizeof(int)*1024);
  uint32_t* csrp = (uint32_t*)carve(sizeof(uint32_t)*(size_t)ETOT);
  f16*      h_a  = (f16*)carve(2*(size_t)NTOT*HID);
  f16*      h_b  = (f16*)carve(2*(size_t)NTOT*HID);
  f16*      jk16 = (f16*)carve(2*(size_t)NTOT*HID);

  hipMemsetAsync(deg, 0, sizeof(int)*NTOT, stream);
  k_hist <<<ETOT/256,  256, 0, stream>>>(edst, deg);
  k_scan1<<<NCHUNK,    256, 0, stream>>>(deg, part);
  k_scan2<<<1,        1024, 0, stream>>>(part, NCHUNK);
  k_scan3<<<NCHUNK,    256, 0, stream>>>(deg, part, off);
  // reuse deg as the fill cursor
  hipMemcpyAsync(deg, off, sizeof(int)*NTOT, hipMemcpyDeviceToDevice, stream);
  k_fill <<<ETOT/256,  256, 0, stream>>>(esrc, edst, deg, csrp);

  k_layer0<<<NTOT/NPB, 256, 0, stream>>>(x, off, csrp, wl0, bl0, wr0, h_a, jk16);
  f16* hc = h_a; f16* hn = h_b;
  for (int l=0; l<4; l++){
    k_layer<<<NTOT/NPB, 256, 0, stream>>>(hc, off, csrp,
                                          wl + l*HID*HID, bl + l*HID, wr + l*HID*HID,
                                          hn, jk16);
    f16* tmp = hc; hc = hn; hn = tmp;
  }
  k_attn<<<BGRAPH, 256, 0, stream>>>(jk16, x, shf,
                                     wq, bq, wk, bk, wv, bv, wo, bo, wfc, bfc, out);
}